// Round 1
// 943.767 us; speedup vs baseline: 1.0759x; 1.0759x over previous
//
#include <hip/hip_runtime.h>
#include <stdint.h>

#define NHEADS 16
#define HDIM 32
#define NTOK 64
#define NWIN_B 2048
#define MROWS (NWIN_B * NTOK)   // 131072
#define CDIM 512
#define QKVDIM 1536
#define ATT_SCALE 0.17677669529663687f

typedef __attribute__((ext_vector_type(8))) short short8;
typedef __attribute__((ext_vector_type(4))) float f32x4;

__device__ __forceinline__ unsigned short f2bf(float f) {
  unsigned int u = __float_as_uint(f);
  u += 0x7FFFu + ((u >> 16) & 1u);   // RNE
  return (unsigned short)(u >> 16);
}

__device__ __forceinline__ void gload_lds16(const unsigned short* g, unsigned short* l) {
  __builtin_amdgcn_global_load_lds(
      (const __attribute__((address_space(1))) unsigned int*)g,
      (__attribute__((address_space(3))) unsigned int*)l, 16, 0, 0);
}

// ---------- fp32 -> bf16 convert ----------
__global__ void cvt_bf16_kernel(const float* __restrict__ src,
                                unsigned short* __restrict__ dst, int n4) {
  int i = blockIdx.x * blockDim.x + threadIdx.x;
  if (i >= n4) return;
  const float4 v = ((const float4*)src)[i];
  ushort4 o;
  o.x = f2bf(v.x); o.y = f2bf(v.y); o.z = f2bf(v.z); o.w = f2bf(v.w);
  ((ushort4*)dst)[i] = o;
}

// ---------- Swin relative-position bias expansion: bias[h][row][col] ----------
__global__ void expand_bias_kernel(const float* __restrict__ table,
                                   float* __restrict__ biasx) {
  const int t = blockIdx.x * blockDim.x + threadIdx.x;   // [0, 16*64*64)
  const int col = t & 63, row = (t >> 6) & 63, h = t >> 12;
  const int idx = ((row >> 3) - (col >> 3) + 7) * 15 + ((row & 7) - (col & 7) + 7);
  biasx[t] = table[idx * NHEADS + h];
}

// ---------- 256x256 8-phase GEMM: C = A[M,K] @ B[N,K]^T + bias, bf16 in ----------
// 512 threads = 8 waves (2M x 4N), BK=64, double-buffered 128 KiB LDS.
// LDS rows XOR-swizzled via pre-swizzled global source (linear LDS dest as
// global_load_lds requires): position p of row r holds global 16B-chunk p^(r&7).
// Per K-tile: 4 phases {ds_read subtile | stage 1 half-tile | barrier |
// lgkmcnt(0) | setprio(1) 16xMFMA setprio(0) | barrier}, counted vmcnt(4) only
// at the tile boundary (T3+T4); vmcnt(0) only at the last boundary.
// Stage schedule (derived from consumption: A halves last read ph3, B ph2):
//   ph1: A(t+1) half0   ph2: A(t+1) half1   ph3: B(t+2) half0   ph4: B(t+2) half1

#define MMAQ(qm, qn)                                                          \
  do {                                                                        \
    _Pragma("unroll") for (int kk = 0; kk < 2; ++kk)                          \
    _Pragma("unroll") for (int mt = 0; mt < 4; ++mt)                          \
    _Pragma("unroll") for (int nt = 0; nt < 2; ++nt)                          \
      acc[(qm) * 4 + mt][(qn) * 2 + nt] =                                     \
          __builtin_amdgcn_mfma_f32_16x16x32_bf16(                            \
              aF[mt][kk], bF[(qn) * 2 + nt][kk],                              \
              acc[(qm) * 4 + mt][(qn) * 2 + nt], 0, 0, 0);                    \
  } while (0)

#define LDB_Q(buf, qn)                                                        \
  do {                                                                        \
    _Pragma("unroll") for (int nt = 0; nt < 2; ++nt) {                        \
      const int rb_ = wn * 64 + ((qn) * 2 + nt) * 16 + l16;                   \
      _Pragma("unroll") for (int kk = 0; kk < 2; ++kk) {                      \
        const int pb_ = ((kk * 4 + quad) ^ (l16 & 7)) * 8;                    \
        bF[(qn) * 2 + nt][kk] =                                               \
            *(const short8*)&lds[(buf) * BUFSZ + ATILE + rb_ * 64 + pb_];     \
      }                                                                       \
    }                                                                         \
  } while (0)

template <typename OutT>
__global__ __launch_bounds__(512, 2) void gemm256_kernel(
    const unsigned short* __restrict__ A,
    const unsigned short* __restrict__ Bt,
    const float* __restrict__ bias,
    OutT* __restrict__ C, int M, int N, int K, int nxb) {
  constexpr int BK = 64;
  constexpr int ATILE = 256 * BK;        // 16384 ushorts (32 KB)
  constexpr int BUFSZ = 2 * ATILE;       // A+B per buffer
  __shared__ __align__(16) unsigned short lds[2 * BUFSZ];  // 128 KiB

  const int tid = threadIdx.x;
  const int w = tid >> 6, lane = tid & 63;
  const int quad = lane >> 4, l16 = lane & 15;
  const int wm = w >> 2, wn = w & 3;
  const int srow8 = lane >> 3, gch = (lane & 7) ^ srow8;

  // XCD-aware remap (bijective: grid % 8 == 0 for both GEMMs here)
  const int nyb_per_xcd = (gridDim.x / nxb) >> 3;
  const int xcd = blockIdx.x & 7;
  const int idx = blockIdx.x >> 3;
  const long rowBase = (long)(xcd * nyb_per_xcd + idx / nxb) * 256;
  const long colBase = (long)(idx % nxb) * 256;
  const int NT = K / BK;   // 8 here; schedule requires NT >= 2

  const unsigned short* aSrc = A + (rowBase + w * 8 + srow8) * (long)K + gch * 8;
  const unsigned short* bSrc = Bt + (colBase + w * 8 + srow8) * (long)K + gch * 8;

  auto stageA = [&](int buf, int half, int kt) {
    unsigned short* dst = &lds[buf * BUFSZ + (half * 128 + w * 8) * BK];
    const unsigned short* src = aSrc + (long)half * 128 * K + kt * BK;
    gload_lds16(src, dst);
    gload_lds16(src + 64 * (long)K, dst + 64 * BK);
  };
  auto stageB = [&](int buf, int half, int kt) {
    unsigned short* dst = &lds[buf * BUFSZ + ATILE + (half * 128 + w * 8) * BK];
    const unsigned short* src = bSrc + (long)half * 128 * K + kt * BK;
    gload_lds16(src, dst);
    gload_lds16(src + 64 * (long)K, dst + 64 * BK);
  };

  f32x4 acc[8][4] = {};
  short8 aF[4][2], bF[4][2];

  auto ldA = [&](int buf, int qm) {   // qm only affects addresses (reg idx static)
#pragma unroll
    for (int mt = 0; mt < 4; ++mt) {
      const int r = wm * 128 + qm * 64 + mt * 16 + l16;
#pragma unroll
      for (int kk = 0; kk < 2; ++kk) {
        const int p = ((kk * 4 + quad) ^ (l16 & 7)) * 8;
        aF[mt][kk] = *(const short8*)&lds[buf * BUFSZ + r * 64 + p];
      }
    }
  };

  // -------- prologue: tile0 fully + tile1 B halves; keep 4 loads in flight ----
  stageA(0, 0, 0); stageA(0, 1, 0); stageB(0, 0, 0); stageB(0, 1, 0);
  if (NT > 1) { stageB(1, 0, 1); stageB(1, 1, 1); }
  asm volatile("s_waitcnt vmcnt(4)" ::: "memory");
  __builtin_amdgcn_s_barrier();

  for (int u = 0; u < NT; ++u) {
    const int cur = u & 1, nxt = cur ^ 1;

    // phase 1: read A(qm0)+B(qn0) [12 ds_read]; stage A(t+1) half0
    ldA(cur, 0);
    LDB_Q(cur, 0);
    if (u + 1 < NT) stageA(nxt, 0, u + 1);
    asm volatile("s_waitcnt lgkmcnt(8)" ::: "memory");
    __builtin_amdgcn_s_barrier();
    asm volatile("s_waitcnt lgkmcnt(0)" ::: "memory");
    __builtin_amdgcn_sched_barrier(0);
    __builtin_amdgcn_s_setprio(1);
    MMAQ(0, 0);
    __builtin_amdgcn_s_setprio(0);
    __builtin_amdgcn_s_barrier();

    // phase 2: read B(qn1) [4 ds_read]; stage A(t+1) half1
    LDB_Q(cur, 1);
    if (u + 1 < NT) stageA(nxt, 1, u + 1);
    __builtin_amdgcn_s_barrier();
    asm volatile("s_waitcnt lgkmcnt(0)" ::: "memory");
    __builtin_amdgcn_sched_barrier(0);
    __builtin_amdgcn_s_setprio(1);
    MMAQ(0, 1);
    __builtin_amdgcn_s_setprio(0);
    __builtin_amdgcn_s_barrier();

    // phase 3: read A(qm1) [8 ds_read]; stage B(t+2) half0
    ldA(cur, 1);
    if (u + 2 < NT) stageB(cur, 0, u + 2);
    __builtin_amdgcn_s_barrier();
    asm volatile("s_waitcnt lgkmcnt(0)" ::: "memory");
    __builtin_amdgcn_sched_barrier(0);
    __builtin_amdgcn_s_setprio(1);
    MMAQ(1, 1);
    __builtin_amdgcn_s_setprio(0);
    __builtin_amdgcn_s_barrier();

    // phase 4: stage B(t+2) half1; counted vmcnt at tile boundary only
    if (u + 2 < NT) stageB(cur, 1, u + 2);
    __builtin_amdgcn_s_barrier();
    __builtin_amdgcn_s_setprio(1);
    MMAQ(1, 0);
    __builtin_amdgcn_s_setprio(0);
    if (u + 1 < NT) {
      if (u + 2 < NT) asm volatile("s_waitcnt vmcnt(4)" ::: "memory");
      else            asm volatile("s_waitcnt vmcnt(0)" ::: "memory");
    }
    __builtin_amdgcn_s_barrier();
  }

  // -------- epilogue --------
  if constexpr (sizeof(OutT) == 2) {
    // repack through LDS (128 KiB free) -> 16B/lane coalesced stores
    unsigned short* Cs = &lds[0];   // 256x256 bf16 = 128 KiB exactly
#pragma unroll
    for (int ni = 0; ni < 4; ++ni) {
      const int col = wn * 64 + ni * 16 + l16;
      const float bv = bias[colBase + col];
#pragma unroll
      for (int mi = 0; mi < 8; ++mi) {
        const int row0 = wm * 128 + mi * 16 + quad * 4;
#pragma unroll
        for (int r = 0; r < 4; ++r)
          Cs[(row0 + r) * 256 + col] = f2bf(acc[mi][ni][r] + bv);
      }
    }
    __syncthreads();
#pragma unroll
    for (int t = 0; t < 16; ++t) {
      const int ci = t * 512 + tid;          // 8192 chunks of 16B
      const int row = ci >> 5, ch = ci & 31;
      *(short8*)((unsigned short*)C + (rowBase + row) * N + colBase + ch * 8) =
          *(const short8*)&Cs[ci * 8];
    }
  } else {
#pragma unroll
    for (int ni = 0; ni < 4; ++ni) {
      const long col = colBase + wn * 64 + ni * 16 + l16;
      const float bv = bias[col];
#pragma unroll
      for (int mi = 0; mi < 8; ++mi) {
        const long row0 = rowBase + wm * 128 + mi * 16 + quad * 4;
#pragma unroll
        for (int r = 0; r < 4; ++r)
          C[(row0 + r) * N + col] = acc[mi][ni][r] + bv;
      }
    }
  }
}

// ---------- attention: one block = one window x 4 heads, all data via LDS ----------
__global__ __launch_bounds__(256) void attn_kernel(
    const unsigned short* __restrict__ qkv,   // [MROWS][1536] bf16
    const float* __restrict__ biasx,          // [16][64][64]
    unsigned short* __restrict__ aout) {      // [MROWS][512] bf16
  __shared__ __align__(16) unsigned short sT[3 * 64 * 128];  // 48 KB
  unsigned short* P = sT;  // overlay: P[w][64][72] after tiles consumed

  const int tid = threadIdx.x;
  const int w = tid >> 6, lane = tid & 63;
  const int quad = lane >> 4, l16 = lane & 15;
  const int b = blockIdx.x >> 2;
  const int q = blockIdx.x & 3;       // head group: heads q*4 .. q*4+3
  const int h = q * 4 + w;

  const unsigned short* base = qkv + (long)b * NTOK * QKVDIM + q * 128;

  const int rloc = lane >> 4;         // row within instr
  const int ch = lane & 15;           // LDS 16B-chunk position
#pragma unroll
  for (int t = 0; t < 3; ++t) {
#pragma unroll
    for (int i = 0; i < 4; ++i) {
      const int r = w * 16 + i * 4 + rloc;
      const int gc = ch ^ (r & 15);
      gload_lds16(base + (long)r * QKVDIM + t * 512 + gc * 8,
                  &sT[t * 8192 + (w * 16 + i * 4) * 128]);
    }
  }
  __syncthreads();

  short8 qF[4], kF[4];
  const int pQ = ((w * 4 + quad) ^ l16) * 8;
#pragma unroll
  for (int t = 0; t < 4; ++t) {
    qF[t] = *(const short8*)&sT[0 * 8192 + (t * 16 + l16) * 128 + pQ];
    kF[t] = *(const short8*)&sT[1 * 8192 + (t * 16 + l16) * 128 + pQ];
  }

  f32x4 S[4][4];
#pragma unroll
  for (int mi = 0; mi < 4; ++mi)
#pragma unroll
    for (int ni = 0; ni < 4; ++ni) {
      f32x4 z = {0.f, 0.f, 0.f, 0.f};
      S[mi][ni] = __builtin_amdgcn_mfma_f32_16x16x32_bf16(qF[mi], kF[ni], z, 0, 0, 0);
    }

  short8 vF[2][2];
#pragma unroll
  for (int kt = 0; kt < 2; ++kt)
#pragma unroll
    for (int dt = 0; dt < 2; ++dt) {
      short8 f;
#pragma unroll
      for (int j = 0; j < 8; ++j) {
        const int n = kt * 32 + quad * 8 + j;
        const int c = w * 4 + dt * 2 + (l16 >> 3);
        f[j] = (short)sT[2 * 8192 + n * 128 + (c ^ (n & 15)) * 8 + (l16 & 7)];
      }
      vF[kt][dt] = f;
    }

  __syncthreads();  // all tile reads done; P may overwrite sT

  const float* bh = biasx + h * (NTOK * NTOK);
#pragma unroll
  for (int mi = 0; mi < 4; ++mi) {
#pragma unroll
    for (int r = 0; r < 4; ++r) {
      const int row = mi * 16 + quad * 4 + r;
      float vals[4], mx = -3.4e38f;
#pragma unroll
      for (int ni = 0; ni < 4; ++ni) {
        const float s = S[mi][ni][r] * ATT_SCALE + bh[row * 64 + ni * 16 + l16];
        vals[ni] = s;
        mx = fmaxf(mx, s);
      }
#pragma unroll
      for (int d = 1; d < 16; d <<= 1) mx = fmaxf(mx, __shfl_xor(mx, d));
      float sum = 0.f;
#pragma unroll
      for (int ni = 0; ni < 4; ++ni) { vals[ni] = __expf(vals[ni] - mx); sum += vals[ni]; }
#pragma unroll
      for (int d = 1; d < 16; d <<= 1) sum += __shfl_xor(sum, d);
      const float inv = 1.0f / sum;
#pragma unroll
      for (int ni = 0; ni < 4; ++ni)
        P[w * 4608 + row * 72 + ni * 16 + l16] = f2bf(vals[ni] * inv);
    }
  }

  f32x4 O[4][2] = {};
#pragma unroll
  for (int mi = 0; mi < 4; ++mi)
#pragma unroll
    for (int kt = 0; kt < 2; ++kt) {
      const short8 pF = *(const short8*)&P[w * 4608 + (mi * 16 + l16) * 72 + kt * 32 + quad * 8];
#pragma unroll
      for (int dt = 0; dt < 2; ++dt)
        O[mi][dt] = __builtin_amdgcn_mfma_f32_16x16x32_bf16(pF, vF[kt][dt], O[mi][dt], 0, 0, 0);
    }

#pragma unroll
  for (int mi = 0; mi < 4; ++mi)
#pragma unroll
    for (int dt = 0; dt < 2; ++dt)
#pragma unroll
      for (int r = 0; r < 4; ++r) {
        const int row = mi * 16 + quad * 4 + r;
        aout[((long)b * NTOK + row) * CDIM + h * HDIM + dt * 16 + l16] = f2bf(O[mi][dt][r]);
      }
}

extern "C" void kernel_launch(void* const* d_in, const int* in_sizes, int n_in,
                              void* d_out, int out_size, void* d_ws, size_t ws_size,
                              hipStream_t stream) {
  const float* x      = (const float*)d_in[0];
  const float* W_qkv  = (const float*)d_in[1];
  const float* b_qkv  = (const float*)d_in[2];
  const float* W_proj = (const float*)d_in[3];
  const float* b_proj = (const float*)d_in[4];
  const float* btab   = (const float*)d_in[5];

  char* ws = (char*)d_ws;
  unsigned short* qkv   = (unsigned short*)ws;
  unsigned short* xb    = (unsigned short*)(ws + 402653184L);
  unsigned short* aout  = xb;  // xb dead after qkv GEMM; alias to save workspace
  unsigned short* wqkvb = (unsigned short*)(ws + 402653184L + 134217728L);
  unsigned short* wprjb = (unsigned short*)(ws + 402653184L + 134217728L + 1572864L);
  float*          biasx = (float*)(ws + 402653184L + 134217728L + 1572864L + 524288L);

  cvt_bf16_kernel<<<(MROWS * CDIM) / 1024, 256, 0, stream>>>(x, xb, (MROWS * CDIM) / 4);
  cvt_bf16_kernel<<<(QKVDIM * CDIM) / 1024, 256, 0, stream>>>(W_qkv, wqkvb, (QKVDIM * CDIM) / 4);
  cvt_bf16_kernel<<<(CDIM * CDIM) / 1024, 256, 0, stream>>>(W_proj, wprjb, (CDIM * CDIM) / 4);
  expand_bias_kernel<<<(NHEADS * NTOK * NTOK) / 256, 256, 0, stream>>>(btab, biasx);

  // QKV GEMM: [131072,512] x [1536,512]^T -> 3072 blocks (512x6), %8==0
  gemm256_kernel<unsigned short><<<(MROWS / 256) * (QKVDIM / 256), 512, 0, stream>>>(
      xb, wqkvb, b_qkv, qkv, MROWS, QKVDIM, CDIM, QKVDIM / 256);

  attn_kernel<<<NWIN_B * 4, 256, 0, stream>>>(qkv, biasx, aout);

  // proj GEMM: [131072,512] x [512,512]^T -> 1024 blocks (512x2), %8==0
  gemm256_kernel<float><<<(MROWS / 256) * (CDIM / 256), 512, 0, stream>>>(
      aout, wprjb, b_proj, (float*)d_out, MROWS, CDIM, CDIM, CDIM / 256);
}